// Round 1
// baseline (805.646 us; speedup 1.0000x reference)
//
#include <hip/hip_runtime.h>

#define ACT_THRESHOLD 0.99f

// One block per token row (B*M blocks). H floats per row, 4 per thread -> 256 threads for H=1024.
__global__ __launch_bounds__(256) void act_fused_kernel(
    const float* __restrict__ h,
    const float* __restrict__ wh,
    const float* __restrict__ accp,
    const float* __restrict__ rem,
    const float* __restrict__ exi,
    const int*   __restrict__ run,
    const float* __restrict__ W,
    const float* __restrict__ bptr,
    const float* __restrict__ cptr,
    const int*   __restrict__ sptr,
    float* __restrict__ out,
    int BM, int Hdim)
{
    const int t   = blockIdx.x;
    const int tid = threadIdx.x;
    const size_t base = (size_t)t * (size_t)Hdim;

    const int r = (run[t] > 0) ? 1 : 0;

    __shared__ float sred[4];
    __shared__ float s_update;
    __shared__ float s_runf;

    float4 hv = make_float4(0.f, 0.f, 0.f, 0.f);

    if (r) {
        hv = reinterpret_cast<const float4*>(h + base)[tid];
        const float4 wv = reinterpret_cast<const float4*>(W)[tid];
        float part = hv.x * wv.x + hv.y * wv.y + hv.z * wv.z + hv.w * wv.w;
        // wave64 butterfly reduce
        #pragma unroll
        for (int off = 32; off > 0; off >>= 1)
            part += __shfl_down(part, off, 64);
        if ((tid & 63) == 0) sred[tid >> 6] = part;
    }
    __syncthreads();

    if (tid == 0) {
        float p = 0.f;
        if (r) {
            const float dot = sred[0] + sred[1] + sred[2] + sred[3];
            const float bb = bptr[0];
            const float cf = cptr[0];
            p = (1.0f / (1.0f + expf(-(dot + bb)))) * cf;
        }
        const float ap  = accp[t];
        const bool mcb = ((ap + p) < ACT_THRESHOLD) && (r != 0);
        const bool meb = (!mcb) && (r != 0);
        const float update = mcb ? p : (meb ? (1.0f - ap) : 0.0f);
        const int   rnew   = mcb ? r : 0;
        const float accnew = mcb ? (ap + p) : ap;
        const float remnew = rem[t] + (meb ? (1.0f - accnew) : 0.0f);

        // step may be int32/int64 (low word = value) or float32; decode heuristically
        const int iv = sptr[0];
        float stepf;
        if (iv > -16777216 && iv < 16777216) stepf = (float)iv;
        else stepf = __int_as_float(iv);

        const float exnew = exi[t] + (meb ? stepf : 0.0f);

        const size_t so = (size_t)2 * (size_t)BM * (size_t)Hdim;
        out[so + 0 * (size_t)BM + t] = accnew;
        out[so + 1 * (size_t)BM + t] = remnew;
        out[so + 2 * (size_t)BM + t] = exnew;
        out[so + 3 * (size_t)BM + t] = (float)rnew;

        s_update = update;
        s_runf   = (float)rnew;
    }
    __syncthreads();

    const float upd = s_update;
    const float rnf = s_runf;

    const float4 wv = reinterpret_cast<const float4*>(wh + base)[tid];
    float4 o;
    o.x = hv.x * upd + wv.x;
    o.y = hv.y * upd + wv.y;
    o.z = hv.z * upd + wv.z;
    o.w = hv.w * upd + wv.w;
    reinterpret_cast<float4*>(out + (size_t)BM * (size_t)Hdim + base)[tid] = o;

    float4 ho;
    ho.x = hv.x * rnf;
    ho.y = hv.y * rnf;
    ho.z = hv.z * rnf;
    ho.w = hv.w * rnf;
    reinterpret_cast<float4*>(out + base)[tid] = ho;
}

extern "C" void kernel_launch(void* const* d_in, const int* in_sizes, int n_in,
                              void* d_out, int out_size, void* d_ws, size_t ws_size,
                              hipStream_t stream) {
    const float* h    = (const float*)d_in[0];
    const float* wh   = (const float*)d_in[1];
    const float* accp = (const float*)d_in[2];
    const float* rem  = (const float*)d_in[3];
    const float* exi  = (const float*)d_in[4];
    const int*   run  = (const int*)d_in[5];
    const float* W    = (const float*)d_in[6];
    const float* bptr = (const float*)d_in[7];
    const float* cptr = (const float*)d_in[8];
    const int*   sptr = (const int*)d_in[9];
    float* out = (float*)d_out;

    const int BM   = in_sizes[2];            // B*M (acc_p element count)
    const int Hdim = in_sizes[0] / BM;       // 1024

    const int threads = Hdim / 4;            // 256 for H=1024
    act_fused_kernel<<<dim3(BM), dim3(threads), 0, stream>>>(
        h, wh, accp, rem, exi, run, W, bptr, cptr, sptr, out, BM, Hdim);
}